// Round 10
// baseline (323.213 us; speedup 1.0000x reference)
//
#include <hip/hip_runtime.h>

// CTC forward NLL — ABLATION ROUND. k_abl<0> = R7 best (real output).
// k_abl<1..4> = diagnostic variants at fixed len=1024 writing to a sink:
//   1: no RESCALE     2: no step-DPP (p3=0)   3: no LDS reads (const probs)
//   4: bare VALU chain (no memory, no rescale, no DPP)
// Per-dispatch rocprof rows decompose the 196 cy/step into components.

#define LOG2E 1.4426950408889634f
#define LN2   0.6931471805599453f

constexpr int B = 32, T = 1024, NV = 1024, L = 128;
constexpr int S = 2 * L + 1;   // 257
constexpr int TS = 64;         // timesteps staged per LDS block

__device__ inline float fexp2(float x) { return __builtin_amdgcn_exp2f(x); }
__device__ inline float flog2(float x) { return __builtin_amdgcn_logf(x); }

template<int CTRL>
__device__ inline float dpp_mov(float old_, float x) {
    return __int_as_float(__builtin_amdgcn_update_dpp(
        __float_as_int(old_), __float_as_int(x), CTRL, 0xF, 0xF, false));
}

// ---- Kernel 1: softmax denominator + linear-prob gather ---------------------
__global__ __launch_bounds__(256) void k_lse_gather(
    const float* __restrict__ logits, const int* __restrict__ targets,
    const int* __restrict__ tgtlen,
    float* __restrict__ pQ, float* __restrict__ pB)
{
    const int row = blockIdx.x;          // b*T + t
    const int b   = row >> 10;           // T = 1024
    const float* x = logits + (size_t)row * NV;
    const int tid = threadIdx.x;

    float4 v = reinterpret_cast<const float4*>(x)[tid];
    float m = fmaxf(fmaxf(v.x, v.y), fmaxf(v.z, v.w));
    #pragma unroll
    for (int off = 32; off; off >>= 1) m = fmaxf(m, __shfl_xor(m, off));

    __shared__ float red[8];
    const int lane = tid & 63, wv = tid >> 6;
    if (lane == 0) red[wv] = m;
    __syncthreads();
    m = fmaxf(fmaxf(red[0], red[1]), fmaxf(red[2], red[3]));

    float s = fexp2((v.x - m) * LOG2E) + fexp2((v.y - m) * LOG2E)
            + fexp2((v.z - m) * LOG2E) + fexp2((v.w - m) * LOG2E);
    #pragma unroll
    for (int off = 32; off; off >>= 1) s += __shfl_xor(s, off);
    if (lane == 0) red[4 + wv] = s;
    __syncthreads();
    s = red[4] + red[5] + red[6] + red[7];

    const float lse2 = m * LOG2E + flog2(s);
    if (tid == 0) {
        pB[row] = fexp2(x[0] * LOG2E - lse2);               // blank prob
    } else if (tid <= L) {
        const int j  = tid - 1;
        const int tl = tgtlen[b];
        const int lab = targets[b * L + j];
        pQ[(size_t)row * 128 + j] =
            (j < tl) ? fexp2(x[lab] * LOG2E - lse2) : 0.0f;
    }
}

// ---- Kernel 2 (templated ablation): linear-domain alpha recursion -----------
template<int VAR>
__global__ __launch_bounds__(64) void k_abl(
    const float* __restrict__ pQ, const float* __restrict__ pB,
    const int* __restrict__ targets, const int* __restrict__ loglen,
    const int* __restrict__ tgtlen, float* __restrict__ out,
    float* __restrict__ sink)
{
    const int b  = blockIdx.x;
    const int l  = threadIdx.x;
    const int len = (VAR == 0) ? loglen[b] : T;   // variants: fixed full length
    const int tl  = tgtlen[b];

    const int* tg = targets + b * L;
    const int t2l   = tg[2 * l];
    const int t2lm1 = (l > 0) ? tg[2 * l - 1] : -3;
    const int t2lp1 = tg[2 * l + 1];
    const float cs1f = (t2l != t2lm1) ? 1.0f : 0.0f;
    const float cs3f = (t2lp1 != t2l) ? 1.0f : 0.0f;

    float A0 = (l == 0) ? pB[(size_t)b * T] : 0.0f;
    float A1 = (l == 0) ? pQ[(size_t)b * T * 128] : 0.0f;
    float A2 = 0.0f, A3 = 0.0f, A4 = 0.0f;
    float p3 = 0.0f;
    int Se = 0;

    __shared__ __align__(16) float sQ[2][TS][128];   // 64 KB
    __shared__ __align__(16) float sB[2][TS];
    __shared__ float alpha[S];

    const float* gQ = pQ + (size_t)b * T * 128 + (l & 31) * 4;

    #define STAGE(buf, t0)                                                     \
    {                                                                          \
        _Pragma("unroll")                                                      \
        for (int c = 0; c < TS / 2; ++c) {                                     \
            const int r  = (t0) + 2 * c + (l >> 5);                            \
            const int rc = (r < T) ? r : (T - 1);                              \
            const float* gp = gQ + (size_t)rc * 128;                           \
            __builtin_amdgcn_global_load_lds(                                  \
                (const __attribute__((address_space(1))) void*)gp,             \
                (__attribute__((address_space(3))) void*)&sQ[buf][2 * c][0],   \
                16, 0, 0);                                                     \
        }                                                                      \
        {                                                                      \
            const int r  = (t0) + l;                                           \
            const int rc = (r < T) ? r : (T - 1);                              \
            const float* gp = pB + (size_t)b * T + rc;                         \
            __builtin_amdgcn_global_load_lds(                                  \
                (const __attribute__((address_space(1))) void*)gp,             \
                (__attribute__((address_space(3))) void*)&sB[buf][0],          \
                4, 0, 0);                                                      \
        }                                                                      \
    }

    float2 qa[8]; float ba[8];
    float2 qb[8]; float bbf[8];

    #define LOADG(QD, BD, cbuf, r0)                                            \
    {                                                                          \
        _Pragma("unroll")                                                      \
        for (int r = 0; r < 8; ++r) {                                          \
            QD[r] = *reinterpret_cast<const float2*>(&sQ[cbuf][(r0) + r][2*l]);\
            BD[r] = sB[cbuf][(r0) + r];                                        \
        }                                                                      \
    }

    #define STEP_ONE(pb_, p1_, pl3_)                                           \
    {                                                                          \
        const float n0 = (A0 + p3) * (pb_);                                    \
        const float n1 = fmaf(cs1f, p3, A1 + A0) * (p1_);                      \
        const float n2 = (A2 + A1) * (pb_);                                    \
        const float n3 = fmaf(cs3f, A1, A3 + A2) * (pl3_);                     \
        const float n4 = (A4 + A3) * (pb_);                                    \
        A0 = n0; A1 = n1; A2 = n2; A3 = n3; A4 = n4;                           \
        if constexpr (VAR == 2)      p3 = 0.0f;                                \
        else if constexpr (VAR == 4) p3 = A3 * 0.25f;                          \
        else                         p3 = dpp_mov<0x138>(0.0f, A3);            \
    }

    #define CALLSTEP(BARR, QARR, i)                                            \
    {                                                                          \
        if constexpr (VAR >= 3) { STEP_ONE(0.999f, 0.998f, 0.997f); }          \
        else                    { STEP_ONE(BARR[i], QARR[i].x, QARR[i].y); }   \
    }

    #define RESCALE()                                                          \
    if constexpr (VAR != 1 && VAR != 4)                                        \
    {                                                                          \
        float m_ = fmaxf(fmaxf(A0, A1), fmaxf(A2, fmaxf(A3, A4)));             \
        m_ = fmaxf(m_, dpp_mov<0x111>(m_, m_));                                \
        m_ = fmaxf(m_, dpp_mov<0x112>(m_, m_));                                \
        m_ = fmaxf(m_, dpp_mov<0x114>(m_, m_));                                \
        m_ = fmaxf(m_, dpp_mov<0x118>(m_, m_));                                \
        m_ = fmaxf(m_, dpp_mov<0x142>(m_, m_));                                \
        m_ = fmaxf(m_, dpp_mov<0x143>(m_, m_));                                \
        const int e = (__builtin_amdgcn_readlane(__float_as_int(m_), 63)       \
                       >> 23) & 0xff;                                          \
        int kb = 374 - e;                                                      \
        if (kb > 254) kb = 254;                                                \
        const float sc = __int_as_float(kb << 23);                             \
        A0 *= sc; A1 *= sc; A2 *= sc; A3 *= sc; A4 *= sc; p3 *= sc;            \
        Se -= (kb - 127);                                                      \
    }

    if constexpr (VAR < 4) { STAGE(0, 1); }
    int cb = 0;

    int tb = 1;
    for (; tb + TS <= len; tb += TS) {
        if constexpr (VAR < 4) {
            asm volatile("s_waitcnt vmcnt(0)" ::: "memory");
            STAGE(cb ^ 1, tb + TS);
        }
        if constexpr (VAR < 3) { LOADG(qa, ba, cb, 0); }
        #pragma unroll
        for (int g = 0; g < 8; ++g) {
            if constexpr (VAR < 3) {
                if (g < 7) {
                    if (g & 1) { LOADG(qa, ba, cb, (g + 1) * 8); }
                    else       { LOADG(qb, bbf, cb, (g + 1) * 8); }
                }
            }
            #pragma unroll
            for (int i = 0; i < 8; ++i) {
                if (g & 1) { CALLSTEP(bbf, qb, i); }
                else       { CALLSTEP(ba,  qa, i); }
            }
            RESCALE();
        }
        cb ^= 1;
    }
    if (tb < len) {                      // guarded tail block
        if constexpr (VAR < 4) {
            asm volatile("s_waitcnt vmcnt(0)" ::: "memory");
        }
        if constexpr (VAR < 3) { LOADG(qa, ba, cb, 0); }
        #pragma unroll
        for (int g = 0; g < 8; ++g) {
            if constexpr (VAR < 3) {
                if (g < 7) {
                    if (g & 1) { LOADG(qa, ba, cb, (g + 1) * 8); }
                    else       { LOADG(qb, bbf, cb, (g + 1) * 8); }
                }
            }
            #pragma unroll
            for (int i = 0; i < 8; ++i) {
                if (tb + g * 8 + i < len) {
                    if (g & 1) { CALLSTEP(bbf, qb, i); }
                    else       { CALLSTEP(ba,  qa, i); }
                }
            }
            if (tb + g * 8 + 7 < len) RESCALE();
        }
    }
    #undef STEP_ONE
    #undef CALLSTEP
    #undef RESCALE
    #undef LOADG
    #undef STAGE

    // keep everything live for ALL variants (rule #17: no DCE'd ablations)
    sink[b * 64 + l] = A0 + A1 + A2 + A3 + A4 + p3 + (float)Se;

    if constexpr (VAR == 0) {
        alpha[4 * l + 0] = A0;
        alpha[4 * l + 1] = A1;
        alpha[4 * l + 2] = A2;
        alpha[4 * l + 3] = A3;
        if (l == 63) alpha[256] = A4;
        __syncthreads();
        if (l == 0) {
            const float sum = alpha[2 * tl] + alpha[2 * tl - 1];
            out[b] = -LN2 * (flog2(sum) + (float)Se);
        }
    }
}

extern "C" void kernel_launch(void* const* d_in, const int* in_sizes, int n_in,
                              void* d_out, int out_size, void* d_ws, size_t ws_size,
                              hipStream_t stream) {
    const float* logits  = (const float*)d_in[0];
    const int*   targets = (const int*)d_in[1];
    const int*   loglen  = (const int*)d_in[2];
    const int*   tgtlen  = (const int*)d_in[3];
    float* out  = (float*)d_out;
    float* pQ   = (float*)d_ws;                              // B*T*128 floats
    float* pB   = pQ + (size_t)B * T * 128;                  // B*T floats
    float* sink = pB + (size_t)B * T;                        // B*64 floats

    k_lse_gather<<<B * T, 256, 0, stream>>>(logits, targets, tgtlen, pQ, pB);
    k_abl<0><<<B, 64, 0, stream>>>(pQ, pB, targets, loglen, tgtlen, out, sink);
    k_abl<1><<<B, 64, 0, stream>>>(pQ, pB, targets, loglen, tgtlen, out, sink);
    k_abl<2><<<B, 64, 0, stream>>>(pQ, pB, targets, loglen, tgtlen, out, sink);
    k_abl<3><<<B, 64, 0, stream>>>(pQ, pB, targets, loglen, tgtlen, out, sink);
    k_abl<4><<<B, 64, 0, stream>>>(pQ, pB, targets, loglen, tgtlen, out, sink);
}

// Round 11
// 93.087 us; speedup vs baseline: 3.4722x; 3.4722x over previous
//
#include <hip/hip_runtime.h>

// CTC forward NLL (warp-ctc semantics), B=32 T=1024 V=1024 L=128, S=2L+1=257.
// Phase 1: per-(b,t) softmax -> LINEAR probs (blank -> pB, 128 target labels
//          -> packed pQ rows, cols >= tgtlen zeroed).
// Phase 2: one wave per batch, 4 s-slots/lane (+1 on lane 63), linear-domain
//          recursion, pow-2 rescale every 8 steps. 64-step LDS double-buffer
//          via global_load_lds. Per-8-step register groups loaded with
//          INLINE-ASM ds_read + explicit lgkmcnt(0) + sched_barrier fences:
//          hipcc re-sinks C++ ds_reads to uses (R7/R10 evidence), exposing
//          ~120cy LDS latency per step; asm + fences pin the pipeline.

#define LOG2E 1.4426950408889634f
#define LN2   0.6931471805599453f

constexpr int B = 32, T = 1024, NV = 1024, L = 128;
constexpr int S = 2 * L + 1;   // 257
constexpr int TS = 64;         // timesteps staged per LDS block

__device__ inline float fexp2(float x) { return __builtin_amdgcn_exp2f(x); }
__device__ inline float flog2(float x) { return __builtin_amdgcn_logf(x); }

template<int CTRL>
__device__ inline float dpp_mov(float old_, float x) {
    return __int_as_float(__builtin_amdgcn_update_dpp(
        __float_as_int(old_), __float_as_int(x), CTRL, 0xF, 0xF, false));
}

// ---- Kernel 1: softmax denominator + linear-prob gather ---------------------
__global__ __launch_bounds__(256) void k_lse_gather(
    const float* __restrict__ logits, const int* __restrict__ targets,
    const int* __restrict__ tgtlen,
    float* __restrict__ pQ, float* __restrict__ pB)
{
    const int row = blockIdx.x;          // b*T + t
    const int b   = row >> 10;           // T = 1024
    const float* x = logits + (size_t)row * NV;
    const int tid = threadIdx.x;

    float4 v = reinterpret_cast<const float4*>(x)[tid];
    float m = fmaxf(fmaxf(v.x, v.y), fmaxf(v.z, v.w));
    #pragma unroll
    for (int off = 32; off; off >>= 1) m = fmaxf(m, __shfl_xor(m, off));

    __shared__ float red[8];
    const int lane = tid & 63, wv = tid >> 6;
    if (lane == 0) red[wv] = m;
    __syncthreads();
    m = fmaxf(fmaxf(red[0], red[1]), fmaxf(red[2], red[3]));

    float s = fexp2((v.x - m) * LOG2E) + fexp2((v.y - m) * LOG2E)
            + fexp2((v.z - m) * LOG2E) + fexp2((v.w - m) * LOG2E);
    #pragma unroll
    for (int off = 32; off; off >>= 1) s += __shfl_xor(s, off);
    if (lane == 0) red[4 + wv] = s;
    __syncthreads();
    s = red[4] + red[5] + red[6] + red[7];

    const float lse2 = m * LOG2E + flog2(s);
    if (tid == 0) {
        pB[row] = fexp2(x[0] * LOG2E - lse2);               // blank prob
    } else if (tid <= L) {
        const int j  = tid - 1;
        const int tl = tgtlen[b];
        const int lab = targets[b * L + j];
        pQ[(size_t)row * 128 + j] =
            (j < tl) ? fexp2(x[lab] * LOG2E - lse2) : 0.0f;
    }
}

// ---- Kernel 2: linear-domain alpha recursion (asm-pipelined LDS reads) ------
__global__ __launch_bounds__(64) void k_ctc_alpha(
    const float* __restrict__ pQ, const float* __restrict__ pB,
    const int* __restrict__ targets, const int* __restrict__ loglen,
    const int* __restrict__ tgtlen, float* __restrict__ out)
{
    const int b  = blockIdx.x;
    const int l  = threadIdx.x;
    const int len = loglen[b];           // [512, 1024]
    const int tl  = tgtlen[b];           // [64, 128]

    const int* tg = targets + b * L;
    const int t2l   = tg[2 * l];
    const int t2lm1 = (l > 0) ? tg[2 * l - 1] : -3;
    const int t2lp1 = tg[2 * l + 1];
    const float cs1f = (t2l != t2lm1) ? 1.0f : 0.0f;
    const float cs3f = (t2lp1 != t2l) ? 1.0f : 0.0f;

    float A0 = (l == 0) ? pB[(size_t)b * T] : 0.0f;
    float A1 = (l == 0) ? pQ[(size_t)b * T * 128] : 0.0f;
    float A2 = 0.0f, A3 = 0.0f, A4 = 0.0f;
    float p3 = 0.0f;
    int Se = 0;

    __shared__ __align__(16) float sQ[2][TS][128];   // 64 KB
    __shared__ __align__(16) float sB[2][TS];
    __shared__ float alpha[S];

    const float* gQ = pQ + (size_t)b * T * 128 + (l & 31) * 4;

    #define STAGE(buf, t0)                                                     \
    {                                                                          \
        _Pragma("unroll")                                                      \
        for (int c = 0; c < TS / 2; ++c) {                                     \
            const int r  = (t0) + 2 * c + (l >> 5);                            \
            const int rc = (r < T) ? r : (T - 1);                              \
            const float* gp = gQ + (size_t)rc * 128;                           \
            __builtin_amdgcn_global_load_lds(                                  \
                (const __attribute__((address_space(1))) void*)gp,             \
                (__attribute__((address_space(3))) void*)&sQ[buf][2 * c][0],   \
                16, 0, 0);                                                     \
        }                                                                      \
        {                                                                      \
            const int r  = (t0) + l;                                           \
            const int rc = (r < T) ? r : (T - 1);                              \
            const float* gp = pB + (size_t)b * T + rc;                         \
            __builtin_amdgcn_global_load_lds(                                  \
                (const __attribute__((address_space(1))) void*)gp,             \
                (__attribute__((address_space(3))) void*)&sB[buf][0],          \
                4, 0, 0);                                                      \
        }                                                                      \
    }

    // double-buffered 8-step register groups
    float2 qa[8]; float ba[8];
    float2 qb[8]; float bbf[8];

    // inline-asm LDS reads: opaque to the scheduler, cannot be re-sunk to uses
    #define DSR64(dst, p)                                                      \
        asm volatile("ds_read_b64 %0, %1" : "=v"(dst)                          \
            : "v"((const __attribute__((address_space(3))) float*)(p)))
    #define DSR32(dst, p)                                                      \
        asm volatile("ds_read_b32 %0, %1" : "=v"(dst)                          \
            : "v"((const __attribute__((address_space(3))) float*)(p)))

    #define ISSUE(QD, BD, cbuf, r0)                                            \
    {                                                                          \
        _Pragma("unroll")                                                      \
        for (int r = 0; r < 8; ++r) {                                          \
            DSR64(QD[r], &sQ[cbuf][(r0) + r][2 * l]);                          \
            DSR32(BD[r], &sB[cbuf][(r0) + r]);                                 \
        }                                                                      \
    }

    // rule #18: lgkmcnt asm wait MUST be followed by sched_barrier(0)
    #define LGKM0 { asm volatile("s_waitcnt lgkmcnt(0)" ::: "memory");         \
                    __builtin_amdgcn_sched_barrier(0); }
    #define SBAR  __builtin_amdgcn_sched_barrier(0)

    #define STEPU(QARR, BARR, i)                                               \
    {                                                                          \
        const float pbv = BARR[i];                                             \
        const float p1v = QARR[i].x;                                           \
        const float plv = QARR[i].y;                                           \
        const float n0 = (A0 + p3) * pbv;                                      \
        const float n1 = fmaf(cs1f, p3, A1 + A0) * p1v;                        \
        const float n2 = (A2 + A1) * pbv;                                      \
        const float n3 = fmaf(cs3f, A1, A3 + A2) * plv;                        \
        const float n4 = (A4 + A3) * pbv;                                      \
        A0 = n0; A1 = n1; A2 = n2; A3 = n3; A4 = n4;                           \
        p3 = dpp_mov<0x138>(0.0f, A3);     /* wave_shr:1, lane0 <- 0 */        \
    }

    #define RESCALE()                                                          \
    {                                                                          \
        float m_ = fmaxf(fmaxf(A0, A1), fmaxf(A2, fmaxf(A3, A4)));             \
        m_ = fmaxf(m_, dpp_mov<0x111>(m_, m_));                                \
        m_ = fmaxf(m_, dpp_mov<0x112>(m_, m_));                                \
        m_ = fmaxf(m_, dpp_mov<0x114>(m_, m_));                                \
        m_ = fmaxf(m_, dpp_mov<0x118>(m_, m_));                                \
        m_ = fmaxf(m_, dpp_mov<0x142>(m_, m_));                                \
        m_ = fmaxf(m_, dpp_mov<0x143>(m_, m_));                                \
        const int e = (__builtin_amdgcn_readlane(__float_as_int(m_), 63)       \
                       >> 23) & 0xff;                                          \
        int kb = 374 - e;                  /* target 2^120 */                  \
        if (kb > 254) kb = 254;                                                \
        const float sc = __int_as_float(kb << 23);                             \
        A0 *= sc; A1 *= sc; A2 *= sc; A3 *= sc; A4 *= sc; p3 *= sc;            \
        Se -= (kb - 127);                                                      \
    }

    STAGE(0, 1);
    int cb = 0;
    int tb = 1;

    for (; tb + TS <= len; tb += TS) {
        asm volatile("s_waitcnt vmcnt(0)" ::: "memory");   // buf cb staged
        STAGE(cb ^ 1, tb + TS);
        ISSUE(qa, ba, cb, 0);
        LGKM0;
        #pragma unroll
        for (int g = 0; g < 8; ++g) {
            if (g < 7) {
                if (g & 1) { ISSUE(qa, ba, cb, (g + 1) * 8); }
                else       { ISSUE(qb, bbf, cb, (g + 1) * 8); }
                SBAR;
            }
            #pragma unroll
            for (int i = 0; i < 8; ++i) {
                if (g & 1) { STEPU(qb, bbf, i); }
                else       { STEPU(qa, ba, i); }
            }
            RESCALE();
            if (g < 7) LGKM0;
        }
        cb ^= 1;
    }

    if (tb < len) {                      // guarded tail (1..63 steps)
        asm volatile("s_waitcnt vmcnt(0)" ::: "memory");
        ISSUE(qa, ba, cb, 0);
        LGKM0;
        #pragma unroll
        for (int g = 0; g < 8; ++g) {
            if (g < 7) {
                if (g & 1) { ISSUE(qa, ba, cb, (g + 1) * 8); }
                else       { ISSUE(qb, bbf, cb, (g + 1) * 8); }
                SBAR;
            }
            #pragma unroll
            for (int i = 0; i < 8; ++i) {
                if (tb + g * 8 + i < len) {      // wave-uniform freeze
                    if (g & 1) { STEPU(qb, bbf, i); }
                    else       { STEPU(qa, ba, i); }
                }
            }
            if (tb + g * 8 + 7 < len) RESCALE();
            if (g < 7) LGKM0;
        }
    }
    #undef STEPU
    #undef RESCALE
    #undef ISSUE
    #undef DSR64
    #undef DSR32
    #undef LGKM0
    #undef SBAR
    #undef STAGE

    asm volatile("s_waitcnt vmcnt(0) lgkmcnt(0)" ::: "memory");  // drain

    alpha[4 * l + 0] = A0;
    alpha[4 * l + 1] = A1;
    alpha[4 * l + 2] = A2;
    alpha[4 * l + 3] = A3;
    if (l == 63) alpha[256] = A4;
    __syncthreads();

    if (l == 0) {
        const float sum = alpha[2 * tl] + alpha[2 * tl - 1];
        out[b] = -LN2 * (flog2(sum) + (float)Se);
    }
}

extern "C" void kernel_launch(void* const* d_in, const int* in_sizes, int n_in,
                              void* d_out, int out_size, void* d_ws, size_t ws_size,
                              hipStream_t stream) {
    const float* logits  = (const float*)d_in[0];
    const int*   targets = (const int*)d_in[1];
    const int*   loglen  = (const int*)d_in[2];
    const int*   tgtlen  = (const int*)d_in[3];
    float* out = (float*)d_out;
    float* pQ = (float*)d_ws;                                // B*T*128 floats
    float* pB = pQ + (size_t)B * T * 128;                    // B*T floats

    k_lse_gather<<<B * T, 256, 0, stream>>>(logits, targets, tgtlen, pQ, pB);
    k_ctc_alpha<<<B, 64, 0, stream>>>(pQ, pB, targets, loglen, tgtlen, out);
}